// Round 7
// baseline (138.619 us; speedup 1.0000x reference)
//
#include <hip/hip_runtime.h>

// All fp32 (established). 7 stream-ordered dispatches.
// Fusion ledger (measured r3-r6): narrow-kernel removal pays; fusions that
// duplicate weight reads or shrink the grid lose. This round: occupancy fix —
// every kernel >=512 blocks (2 blk/CU, 8 waves/CU) for latency hiding.
constexpr int B = 2, S = 2048, E = 1024, H = 16, D = 64;
constexpr int E4 = E / 4;  // 256 float4 per row

__device__ __forceinline__ float dot4(float4 a, float4 w) {
  return a.x * w.x + a.y * w.y + a.z * w.z + a.w * w.w;
}

// ---------------------------------------------------------------------------
// K1 v2: q_vec[b*E + n] = x[b,S-1,:] . Wq[n,:]  — wave per n (proven k_outvec
// geometry), 512 blocks x 256 thr. Also zeroes ctx (atomic target).
__global__ void k_qvec(const float4* __restrict__ x, const float4* __restrict__ Wq,
                       float* __restrict__ q_vec, float4* __restrict__ ctx4) {
  int gid = blockIdx.x * 256 + threadIdx.x;
  if (gid < B * H * E4) ctx4[gid] = make_float4(0.f, 0.f, 0.f, 0.f);
  int gw = gid >> 6;
  int lane = threadIdx.x & 63;
  int b = gw >> 10, nn = gw & 1023;
  const float4* xr = x + ((size_t)b * S + (S - 1)) * E4;
  const float4* wr = Wq + (size_t)nn * E4;
  float acc = 0.f;
#pragma unroll
  for (int j = 0; j < 4; ++j) {
    float4 a = xr[lane + 64 * j];
    float4 w = wr[lane + 64 * j];
    acc += dot4(a, w);
  }
#pragma unroll
  for (int o = 32; o > 0; o >>= 1) acc += __shfl_xor(acc, o, 64);
  if (lane == 0) q_vec[gw] = acc;
}

// ---------------------------------------------------------------------------
// K2 v3: wkq[b,h,e] = sum_d q_vec[b,h*D+d] * Wk[h*D+d,e]; zeroes rowsum.
// 512 blocks = (bh 32, eo 16) x 256 thr; thread = (dq 16 over 4-d groups,
// el 16 over float4 cols); LDS tree over dq.
__global__ __launch_bounds__(256) void k_wkq(const float* __restrict__ q_vec,
                                             const float4* __restrict__ Wk4,
                                             float4* __restrict__ wkq4,
                                             float* __restrict__ rowsum) {
  int bb = blockIdx.x;
  int bh = bb >> 4, eo = bb & 15;
  int b = bh >> 4, h = bh & 15;
  int tid = threadIdx.x;
  __shared__ float qh[D];
  __shared__ float4 red4[256];
  if (tid < D) qh[tid] = q_vec[b * E + h * D + tid];
  if (eo == 0 && tid == 0) rowsum[bh] = 0.f;
  __syncthreads();
  int dq = tid >> 4, el = tid & 15;
  int e4 = eo * 16 + el;
  float4 acc = make_float4(0.f, 0.f, 0.f, 0.f);
#pragma unroll
  for (int i = 0; i < 4; ++i) {
    int d = dq * 4 + i;
    float qd = qh[d];
    float4 wk = Wk4[(size_t)(h * D + d) * E4 + e4];
    acc.x += qd * wk.x; acc.y += qd * wk.y; acc.z += qd * wk.z; acc.w += qd * wk.w;
  }
  red4[tid] = acc;
  __syncthreads();
  if (tid < 128) { float4 a = red4[tid], c = red4[tid + 128];
    red4[tid] = make_float4(a.x + c.x, a.y + c.y, a.z + c.z, a.w + c.w); }
  __syncthreads();
  if (tid < 64) { float4 a = red4[tid], c = red4[tid + 64];
    red4[tid] = make_float4(a.x + c.x, a.y + c.y, a.z + c.z, a.w + c.w); }
  __syncthreads();
  if (tid < 32) { float4 a = red4[tid], c = red4[tid + 32];
    red4[tid] = make_float4(a.x + c.x, a.y + c.y, a.z + c.z, a.w + c.w); }
  __syncthreads();
  if (tid < 16) {
    float4 a = red4[tid], c = red4[tid + 16];
    wkq4[(size_t)bh * E4 + eo * 16 + tid] =
        make_float4(a.x + c.x, a.y + c.y, a.z + c.z, a.w + c.w);
  }
}

// ---------------------------------------------------------------------------
// K3: p[b,h,k] = exp(embK[b,k,:] . wkq[b,h,:]) + per-row sums. (r2 proven)
// 512 blocks x 256 thr, 8 rows/block, 64 KB LDS -> 2 blk/CU, 8 waves/CU.
__global__ __launch_bounds__(256) void k_scores_exp(const float4* __restrict__ embK,
                                                    const float4* __restrict__ wkq4,
                                                    float* __restrict__ p,
                                                    float* __restrict__ rowsum) {
  __shared__ float4 wl4[H * E4];  // 64 KB
  __shared__ float hsum[16];
  int bb = blockIdx.x;
  int b = bb >> 8, k0 = (bb & 255) * 8;
  int tid = threadIdx.x;
  const float4* wsrc = wkq4 + (size_t)b * (H * E4);
#pragma unroll
  for (int j = 0; j < 16; ++j) wl4[j * 256 + tid] = wsrc[j * 256 + tid];
  if (tid < 16) hsum[tid] = 0.f;
  __syncthreads();
  int wv = tid >> 6, lane = tid & 63;
  const float4* e0 = embK + ((size_t)b * S + k0 + wv) * E4;
  const float4* e1 = embK + ((size_t)b * S + k0 + wv + 4) * E4;
  float4 va[4], vb[4];
#pragma unroll
  for (int j = 0; j < 4; ++j) { va[j] = e0[lane + 64 * j]; vb[j] = e1[lane + 64 * j]; }
#pragma unroll 1
  for (int h = 0; h < H; ++h) {
    float a0 = 0.f, a1 = 0.f;
#pragma unroll
    for (int j = 0; j < 4; ++j) {
      float4 w = wl4[h * 256 + lane + 64 * j];
      a0 += dot4(va[j], w); a1 += dot4(vb[j], w);
    }
#pragma unroll
    for (int o = 32; o > 0; o >>= 1) {
      a0 += __shfl_xor(a0, o, 64); a1 += __shfl_xor(a1, o, 64);
    }
    if (lane == 0) {
      float p0 = __expf(a0), p1 = __expf(a1);
      float* pr = p + ((size_t)(b * H + h)) * S + k0 + wv;
      pr[0] = p0; pr[4] = p1;
      atomicAdd(&hsum[h], p0 + p1);
    }
  }
  __syncthreads();
  if (tid < 16) atomicAdd(&rowsum[b * H + tid], hsum[tid]);
}

// ---------------------------------------------------------------------------
// K4 v2: unnormalized ctx over 128-row k chunks (was 256), block-reduced,
// atomicAdd into ctx (zeroed by K1). grid (B,16,16) = 512 blocks -> 2 blk/CU,
// 8 waves/CU (was 1 blk/CU — latency-exposed on the 16.8 MB embV stream).
__global__ __launch_bounds__(256) void k_ctx_atomic(const float4* __restrict__ embV,
                                                    const float* __restrict__ p,
                                                    float* __restrict__ ctx) {
  int b = blockIdx.x, eo = blockIdx.y, kz = blockIdx.z;
  int tid = threadIdx.x;
  int k0 = kz * 128;
  __shared__ float pl[16 * 128];          // p[h][kk], 8 KB
  __shared__ float4 red4[4 * 16 * 16];    // [wave][h][e4l], 16 KB
#pragma unroll
  for (int r = 0; r < 8; ++r) {
    int i = r * 256 + tid;
    pl[i] = p[((size_t)(b * H + (i >> 7))) * S + k0 + (i & 127)];
  }
  __syncthreads();
  const float4* pl4 = (const float4*)pl;  // pl4[h*32 + kk/4]
  int e4l = tid & 15, ks = tid >> 4;
  int e4 = eo * 16 + e4l;
  float4 acc[H];
#pragma unroll
  for (int h = 0; h < H; ++h) acc[h] = make_float4(0.f, 0.f, 0.f, 0.f);
#pragma unroll
  for (int i4 = 0; i4 < 2; ++i4) {
    int kk = ks * 8 + i4 * 4;
    const float4* vbp = embV + ((size_t)b * S + k0 + kk) * E4 + e4;
    float4 v0 = vbp[0 * E4], v1 = vbp[1 * E4], v2 = vbp[2 * E4], v3 = vbp[3 * E4];
    int kq = kk >> 2;
#pragma unroll
    for (int h = 0; h < H; ++h) {
      float4 p4 = pl4[h * 32 + kq];  // broadcast within 16-lane group
      acc[h].x += p4.x * v0.x + p4.y * v1.x + p4.z * v2.x + p4.w * v3.x;
      acc[h].y += p4.x * v0.y + p4.y * v1.y + p4.z * v2.y + p4.w * v3.y;
      acc[h].z += p4.x * v0.z + p4.y * v1.z + p4.z * v2.z + p4.w * v3.z;
      acc[h].w += p4.x * v0.w + p4.y * v1.w + p4.z * v2.w + p4.w * v3.w;
    }
  }
  int lane = tid & 63, wv = tid >> 6;
  // combine the wave's 4 ks-groups (lane bits 4,5): 32 consecutive k rows
#pragma unroll
  for (int h = 0; h < H; ++h) {
    acc[h].x += __shfl_xor(acc[h].x, 16, 64); acc[h].y += __shfl_xor(acc[h].y, 16, 64);
    acc[h].z += __shfl_xor(acc[h].z, 16, 64); acc[h].w += __shfl_xor(acc[h].w, 16, 64);
    acc[h].x += __shfl_xor(acc[h].x, 32, 64); acc[h].y += __shfl_xor(acc[h].y, 32, 64);
    acc[h].z += __shfl_xor(acc[h].z, 32, 64); acc[h].w += __shfl_xor(acc[h].w, 32, 64);
  }
  if (lane < 16) {  // lane == e4l here
#pragma unroll
    for (int h = 0; h < H; ++h) red4[(wv * 16 + h) * 16 + lane] = acc[h];
  }
  __syncthreads();
  {
    int h = tid >> 4, el = tid & 15;
    float4 r = make_float4(0.f, 0.f, 0.f, 0.f);
#pragma unroll
    for (int ww = 0; ww < 4; ++ww) {
      float4 c = red4[(ww * 16 + h) * 16 + el];
      r.x += c.x; r.y += c.y; r.z += c.z; r.w += c.w;
    }
    float* cp = ctx + (((size_t)(b * H + h)) * E4 + eo * 16 + el) * 4;
    atomicAdd(cp + 0, r.x); atomicAdd(cp + 1, r.y);
    atomicAdd(cp + 2, r.z); atomicAdd(cp + 3, r.w);
  }
}

// ---------------------------------------------------------------------------
// K5: o_vec[b*E+n] = (ctx[b,n/64,:] . Wv[n,:]) / rowsum  (wave per n;
// 512 blocks, 2048 waves). (r5 proven)
__global__ void k_ov(const float* __restrict__ ctx, const float4* __restrict__ Wv4,
                     const float* __restrict__ rowsum, float* __restrict__ o_vec) {
  int gw = (blockIdx.x * blockDim.x + threadIdx.x) >> 6;
  int lane = threadIdx.x & 63;
  int b = gw >> 10, nn = gw & 1023;
  int bh = b * H + (nn >> 6);
  const float4* xr = (const float4*)(ctx + (size_t)bh * E);
  const float4* wr = Wv4 + (size_t)nn * E4;
  float acc = 0.f;
#pragma unroll
  for (int j = 0; j < 4; ++j) {
    float4 a = xr[lane + 64 * j];
    float4 w = wr[lane + 64 * j];
    acc += dot4(a, w);
  }
#pragma unroll
  for (int o = 32; o > 0; o >>= 1) acc += __shfl_xor(acc, o, 64);
  if (lane == 0) o_vec[gw] = acc / rowsum[bh];  // deferred softmax normalization
}

// ---------------------------------------------------------------------------
// K6: out_vec[b*E+n] = o_vec[b,:] . Wo[n,:]  (wave per n; Wo read exactly once)
__global__ void k_outvec(const float* __restrict__ o_vec, const float4* __restrict__ Wo4,
                         float* __restrict__ out_vec) {
  int gw = (blockIdx.x * blockDim.x + threadIdx.x) >> 6;
  int lane = threadIdx.x & 63;
  int b = gw >> 10, nn = gw & 1023;
  const float4* xr = (const float4*)(o_vec + (size_t)b * E);
  const float4* wr = Wo4 + (size_t)nn * E4;
  float acc = 0.f;
#pragma unroll
  for (int j = 0; j < 4; ++j) {
    float4 a = xr[lane + 64 * j];
    float4 w = wr[lane + 64 * j];
    acc += dot4(a, w);
  }
#pragma unroll
  for (int o = 32; o > 0; o >>= 1) acc += __shfl_xor(acc, o, 64);
  if (lane == 0) out_vec[gw] = acc;
}

// ---------------------------------------------------------------------------
// K7: broadcast out_vec over all S rows (float4, write-bound ~2.7 us floor).
__global__ void k_bcast(const float4* __restrict__ ov4, float4* __restrict__ out4) {
  int base = blockIdx.x * 1024 + threadIdx.x;
#pragma unroll
  for (int r = 0; r < 4; ++r) {
    int g = base + r * 256;
    out4[g] = ov4[(g >> 19) * E4 + (g & 255)];
  }
}

// ---------------------------------------------------------------------------
extern "C" void kernel_launch(void* const* d_in, const int* in_sizes, int n_in,
                              void* d_out, int out_size, void* d_ws, size_t ws_size,
                              hipStream_t stream) {
  const float* inputs = (const float*)d_in[0];
  const float* embV   = (const float*)d_in[1];
  const float* embK   = (const float*)d_in[2];
  const float* Wq     = (const float*)d_in[3];
  const float* Wk     = (const float*)d_in[4];
  const float* Wv     = (const float*)d_in[5];
  const float* Wo     = (const float*)d_in[6];

  float* ws      = (float*)d_ws;
  float* q_vec   = ws;                    // 2048
  float* wkq     = q_vec + B * E;         // 32768
  float* p       = wkq + B * H * E;       // 65536 (exp scores, unnormalized)
  float* rowsum  = p + B * H * S;         // 32 (pad to 64)
  float* o_vec   = rowsum + 64;           // 2048
  float* out_vec = o_vec + B * E;         // 2048
  float* ctx     = out_vec + B * E;       // 32768 (atomic accumulator)

  k_qvec<<<512, 256, 0, stream>>>((const float4*)inputs, (const float4*)Wq,
                                  q_vec, (float4*)ctx);
  k_wkq<<<512, 256, 0, stream>>>(q_vec, (const float4*)Wk, (float4*)wkq, rowsum);
  k_scores_exp<<<512, 256, 0, stream>>>((const float4*)embK, (const float4*)wkq,
                                        p, rowsum);
  k_ctx_atomic<<<dim3(B, 16, 16), 256, 0, stream>>>((const float4*)embV, p, ctx);
  k_ov<<<512, 256, 0, stream>>>(ctx, (const float4*)Wv, rowsum, o_vec);
  k_outvec<<<512, 256, 0, stream>>>(o_vec, (const float4*)Wo, out_vec);
  k_bcast<<<1024, 256, 0, stream>>>((const float4*)out_vec, (float4*)d_out);
}

// Round 8
// 136.382 us; speedup vs baseline: 1.0164x; 1.0164x over previous
//
#include <hip/hip_runtime.h>

// All fp32 (established). 7 stream-ordered dispatches. MEASURED BEST (r6).
// Ledger r2-r7: narrow-kernel removal (atomic ctx) pays; fusions that
// duplicate weight reads or shrink the grid lose (+5..+20us, measured 3x);
// occupancy widening of the 256-block kernels: +2.2us (r7, refuted).
constexpr int B = 2, S = 2048, E = 1024, H = 16, D = 64;
constexpr int E4 = E / 4;  // 256 float4 per row

__device__ __forceinline__ float dot4(float4 a, float4 w) {
  return a.x * w.x + a.y * w.y + a.z * w.z + a.w * w.w;
}

// ---------------------------------------------------------------------------
// K1: q_vec[b*E + n] = x[b,S-1,:] . Wq[n,:]  (r2 proven geometry)
// grid 256 x 256; block = (b, 8 consecutive n); 32-lane e-split.
// Also zeroes ctx (atomic accumulator target, re-poisoned each launch).
__global__ void k_qvec(const float4* __restrict__ x, const float4* __restrict__ Wq,
                       float* __restrict__ q_vec, float4* __restrict__ ctx4) {
  int blk = blockIdx.x;
  int b = blk >> 7, n0 = (blk & 127) * 8;
  int tid = threadIdx.x;
  int gid = blk * 256 + tid;
  if (gid < B * H * E4) ctx4[gid] = make_float4(0.f, 0.f, 0.f, 0.f);
  int nl = tid >> 5, es = tid & 31;
  const float4* xr = x + ((size_t)b * S + (S - 1)) * E4;
  const float4* wr = Wq + (size_t)(n0 + nl) * E4;
  float acc = 0.f;
#pragma unroll
  for (int j = 0; j < 8; ++j) {
    float4 a = xr[es + 32 * j];
    float4 w = wr[es + 32 * j];
    acc += dot4(a, w);
  }
#pragma unroll
  for (int o = 16; o > 0; o >>= 1) acc += __shfl_xor(acc, o, 64);
  if (es == 0) q_vec[b * E + n0 + nl] = acc;
}

// ---------------------------------------------------------------------------
// K2: wkq[b,h,e] = sum_d q_vec[b,h*D+d] * Wk[h*D+d,e]; zeroes rowsum.
// (r2 proven) float4 loads + LDS tree reduce. grid 256 = (bh 32, eo 8) x 256.
__global__ __launch_bounds__(256) void k_wkq(const float* __restrict__ q_vec,
                                             const float4* __restrict__ Wk4,
                                             float4* __restrict__ wkq4,
                                             float* __restrict__ rowsum) {
  int bb = blockIdx.x;
  int bh = bb >> 3, eo = bb & 7;
  int b = bh >> 4, h = bh & 15;
  int tid = threadIdx.x;
  __shared__ float qh[D];
  __shared__ float4 red4[256];
  if (tid < D) qh[tid] = q_vec[b * E + h * D + tid];
  if (eo == 0 && tid == 0) rowsum[bh] = 0.f;
  __syncthreads();
  int dq = tid >> 5, el = tid & 31;
  int e4 = eo * 32 + el;
  float4 acc = make_float4(0.f, 0.f, 0.f, 0.f);
#pragma unroll
  for (int i = 0; i < 8; ++i) {
    int d = dq * 8 + i;
    float qd = qh[d];
    float4 wk = Wk4[(size_t)(h * D + d) * E4 + e4];
    acc.x += qd * wk.x; acc.y += qd * wk.y; acc.z += qd * wk.z; acc.w += qd * wk.w;
  }
  red4[dq * 32 + el] = acc;
  __syncthreads();
  if (tid < 32) {
    float4 r = make_float4(0.f, 0.f, 0.f, 0.f);
#pragma unroll
    for (int g = 0; g < 8; ++g) {
      float4 c = red4[g * 32 + tid];
      r.x += c.x; r.y += c.y; r.z += c.z; r.w += c.w;
    }
    wkq4[(size_t)bh * E4 + eo * 32 + tid] = r;
  }
}

// ---------------------------------------------------------------------------
// K3: p[b,h,k] = exp(embK[b,k,:] . wkq[b,h,:]) + per-row sums. (r2 proven)
// 512 blocks x 256 thr, 8 rows/block, 64 KB LDS -> 2 blk/CU, 8 waves/CU.
__global__ __launch_bounds__(256) void k_scores_exp(const float4* __restrict__ embK,
                                                    const float4* __restrict__ wkq4,
                                                    float* __restrict__ p,
                                                    float* __restrict__ rowsum) {
  __shared__ float4 wl4[H * E4];  // 64 KB
  __shared__ float hsum[16];
  int bb = blockIdx.x;
  int b = bb >> 8, k0 = (bb & 255) * 8;
  int tid = threadIdx.x;
  const float4* wsrc = wkq4 + (size_t)b * (H * E4);
#pragma unroll
  for (int j = 0; j < 16; ++j) wl4[j * 256 + tid] = wsrc[j * 256 + tid];
  if (tid < 16) hsum[tid] = 0.f;
  __syncthreads();
  int wv = tid >> 6, lane = tid & 63;
  const float4* e0 = embK + ((size_t)b * S + k0 + wv) * E4;
  const float4* e1 = embK + ((size_t)b * S + k0 + wv + 4) * E4;
  float4 va[4], vb[4];
#pragma unroll
  for (int j = 0; j < 4; ++j) { va[j] = e0[lane + 64 * j]; vb[j] = e1[lane + 64 * j]; }
#pragma unroll 1
  for (int h = 0; h < H; ++h) {
    float a0 = 0.f, a1 = 0.f;
#pragma unroll
    for (int j = 0; j < 4; ++j) {
      float4 w = wl4[h * 256 + lane + 64 * j];
      a0 += dot4(va[j], w); a1 += dot4(vb[j], w);
    }
#pragma unroll
    for (int o = 32; o > 0; o >>= 1) {
      a0 += __shfl_xor(a0, o, 64); a1 += __shfl_xor(a1, o, 64);
    }
    if (lane == 0) {
      float p0 = __expf(a0), p1 = __expf(a1);
      float* pr = p + ((size_t)(b * H + h)) * S + k0 + wv;
      pr[0] = p0; pr[4] = p1;
      atomicAdd(&hsum[h], p0 + p1);
    }
  }
  __syncthreads();
  if (tid < 16) atomicAdd(&rowsum[b * H + tid], hsum[tid]);
}

// ---------------------------------------------------------------------------
// K4: unnormalized ctx over 256-row k chunks, block-reduced, then atomicAdd
// into ctx (zeroed by K1). Replaces the part round-trip + 64-block reduce.
// fp-order jitter ~1e-6 << 1.3e-2 threshold. grid (B,16,8) x 256. (r5 proven)
__global__ __launch_bounds__(256) void k_ctx_atomic(const float4* __restrict__ embV,
                                                    const float* __restrict__ p,
                                                    float* __restrict__ ctx) {
  int b = blockIdx.x, eo = blockIdx.y, kz = blockIdx.z;
  int tid = threadIdx.x;
  int k0 = kz * 256;
  __shared__ float pl[16 * 256];          // p[h][kk], 16 KB
  __shared__ float4 red4[4 * 16 * 16];    // [wave][h][e4l], 16 KB
  for (int i = tid; i < 16 * 256; i += 256) {
    pl[i] = p[((size_t)(b * H + (i >> 8))) * S + k0 + (i & 255)];
  }
  __syncthreads();
  const float4* pl4 = (const float4*)pl;  // pl4[h*64 + kk/4]
  int e4l = tid & 15, ks = tid >> 4;
  int e4 = eo * 16 + e4l;
  float4 acc[H];
#pragma unroll
  for (int h = 0; h < H; ++h) acc[h] = make_float4(0.f, 0.f, 0.f, 0.f);
#pragma unroll
  for (int i4 = 0; i4 < 4; ++i4) {
    int kk = ks * 16 + i4 * 4;
    const float4* vbp = embV + ((size_t)b * S + k0 + kk) * E4 + e4;
    float4 v0 = vbp[0 * E4], v1 = vbp[1 * E4], v2 = vbp[2 * E4], v3 = vbp[3 * E4];
    int kq = kk >> 2;
#pragma unroll
    for (int h = 0; h < H; ++h) {
      float4 p4 = pl4[h * 64 + kq];  // broadcast within 16-lane group
      acc[h].x += p4.x * v0.x + p4.y * v1.x + p4.z * v2.x + p4.w * v3.x;
      acc[h].y += p4.x * v0.y + p4.y * v1.y + p4.z * v2.y + p4.w * v3.y;
      acc[h].z += p4.x * v0.z + p4.y * v1.z + p4.z * v2.z + p4.w * v3.z;
      acc[h].w += p4.x * v0.w + p4.y * v1.w + p4.z * v2.w + p4.w * v3.w;
    }
  }
  int lane = tid & 63, wv = tid >> 6;
#pragma unroll
  for (int h = 0; h < H; ++h) {
    acc[h].x += __shfl_xor(acc[h].x, 16, 64); acc[h].y += __shfl_xor(acc[h].y, 16, 64);
    acc[h].z += __shfl_xor(acc[h].z, 16, 64); acc[h].w += __shfl_xor(acc[h].w, 16, 64);
    acc[h].x += __shfl_xor(acc[h].x, 32, 64); acc[h].y += __shfl_xor(acc[h].y, 32, 64);
    acc[h].z += __shfl_xor(acc[h].z, 32, 64); acc[h].w += __shfl_xor(acc[h].w, 32, 64);
  }
  if (lane < 16) {  // lane == e4l here
#pragma unroll
    for (int h = 0; h < H; ++h) red4[(wv * 16 + h) * 16 + lane] = acc[h];
  }
  __syncthreads();
  {
    int h = tid >> 4, el = tid & 15;
    float4 r = make_float4(0.f, 0.f, 0.f, 0.f);
#pragma unroll
    for (int ww = 0; ww < 4; ++ww) {
      float4 c = red4[(ww * 16 + h) * 16 + el];
      r.x += c.x; r.y += c.y; r.z += c.z; r.w += c.w;
    }
    float* cp = ctx + (((size_t)(b * H + h)) * E4 + eo * 16 + el) * 4;
    atomicAdd(cp + 0, r.x); atomicAdd(cp + 1, r.y);
    atomicAdd(cp + 2, r.z); atomicAdd(cp + 3, r.w);
  }
}

// ---------------------------------------------------------------------------
// K5: o_vec[b*E+n] = (ctx[b,n/64,:] . Wv[n,:]) / rowsum  (wave per n;
// 512 blocks, 2048 waves). (r5 proven)
__global__ void k_ov(const float* __restrict__ ctx, const float4* __restrict__ Wv4,
                     const float* __restrict__ rowsum, float* __restrict__ o_vec) {
  int gw = (blockIdx.x * blockDim.x + threadIdx.x) >> 6;
  int lane = threadIdx.x & 63;
  int b = gw >> 10, nn = gw & 1023;
  int bh = b * H + (nn >> 6);
  const float4* xr = (const float4*)(ctx + (size_t)bh * E);
  const float4* wr = Wv4 + (size_t)nn * E4;
  float acc = 0.f;
#pragma unroll
  for (int j = 0; j < 4; ++j) {
    float4 a = xr[lane + 64 * j];
    float4 w = wr[lane + 64 * j];
    acc += dot4(a, w);
  }
#pragma unroll
  for (int o = 32; o > 0; o >>= 1) acc += __shfl_xor(acc, o, 64);
  if (lane == 0) o_vec[gw] = acc / rowsum[bh];  // deferred softmax normalization
}

// ---------------------------------------------------------------------------
// K6: out_vec[b*E+n] = o_vec[b,:] . Wo[n,:]  (wave per n; Wo read exactly once)
__global__ void k_outvec(const float* __restrict__ o_vec, const float4* __restrict__ Wo4,
                         float* __restrict__ out_vec) {
  int gw = (blockIdx.x * blockDim.x + threadIdx.x) >> 6;
  int lane = threadIdx.x & 63;
  int b = gw >> 10, nn = gw & 1023;
  const float4* xr = (const float4*)(o_vec + (size_t)b * E);
  const float4* wr = Wo4 + (size_t)nn * E4;
  float acc = 0.f;
#pragma unroll
  for (int j = 0; j < 4; ++j) {
    float4 a = xr[lane + 64 * j];
    float4 w = wr[lane + 64 * j];
    acc += dot4(a, w);
  }
#pragma unroll
  for (int o = 32; o > 0; o >>= 1) acc += __shfl_xor(acc, o, 64);
  if (lane == 0) out_vec[gw] = acc;
}

// ---------------------------------------------------------------------------
// K7: broadcast out_vec over all S rows (float4, write-bound ~2.7 us floor).
__global__ void k_bcast(const float4* __restrict__ ov4, float4* __restrict__ out4) {
  int base = blockIdx.x * 1024 + threadIdx.x;
#pragma unroll
  for (int r = 0; r < 4; ++r) {
    int g = base + r * 256;
    out4[g] = ov4[(g >> 19) * E4 + (g & 255)];
  }
}

// ---------------------------------------------------------------------------
extern "C" void kernel_launch(void* const* d_in, const int* in_sizes, int n_in,
                              void* d_out, int out_size, void* d_ws, size_t ws_size,
                              hipStream_t stream) {
  const float* inputs = (const float*)d_in[0];
  const float* embV   = (const float*)d_in[1];
  const float* embK   = (const float*)d_in[2];
  const float* Wq     = (const float*)d_in[3];
  const float* Wk     = (const float*)d_in[4];
  const float* Wv     = (const float*)d_in[5];
  const float* Wo     = (const float*)d_in[6];

  float* ws      = (float*)d_ws;
  float* q_vec   = ws;                    // 2048
  float* wkq     = q_vec + B * E;         // 32768
  float* p       = wkq + B * H * E;       // 65536 (exp scores, unnormalized)
  float* rowsum  = p + B * H * S;         // 32 (pad to 64)
  float* o_vec   = rowsum + 64;           // 2048
  float* out_vec = o_vec + B * E;         // 2048
  float* ctx     = out_vec + B * E;       // 32768 (atomic accumulator)

  k_qvec<<<256, 256, 0, stream>>>((const float4*)inputs, (const float4*)Wq,
                                  q_vec, (float4*)ctx);
  k_wkq<<<256, 256, 0, stream>>>(q_vec, (const float4*)Wk, (float4*)wkq, rowsum);
  k_scores_exp<<<512, 256, 0, stream>>>((const float4*)embK, (const float4*)wkq,
                                        p, rowsum);
  k_ctx_atomic<<<dim3(B, 16, 8), 256, 0, stream>>>((const float4*)embV, p, ctx);
  k_ov<<<512, 256, 0, stream>>>(ctx, (const float4*)Wv, rowsum, o_vec);
  k_outvec<<<512, 256, 0, stream>>>(o_vec, (const float4*)Wo, out_vec);
  k_bcast<<<1024, 256, 0, stream>>>((const float4*)out_vec, (float4*)d_out);
}